// Round 10
// baseline (940.120 us; speedup 1.0000x reference)
//
#include <hip/hip_runtime.h>
#include <stdint.h>
#include <stddef.h>

// CNNLSTM: embed -> conv1d(K=5) -> ReLU -> maxpool4 -> LSTM(T=1023,H=128) -> fc(2)
// Inputs: x int32; all float tensors float32. Output f32.
// R10: MFMA recurrence (8 WGs x 8 batches) with (a) bank-swizzled H (rot 8f16
// per row-quad -> 2-way = free), (b) x injected via MFMA C-init from raw
// C-fragment-layout xg (coalesced b64 both sides, bias folded in xg_gemm).

typedef __bf16 bf16;
typedef __bf16 bf16x8 __attribute__((ext_vector_type(8)));
typedef float  f32x4  __attribute__((ext_vector_type(4)));
typedef _Float16 f16;
typedef f16 f16x2 __attribute__((ext_vector_type(2)));
typedef f16 f16x4 __attribute__((ext_vector_type(4)));
typedef f16 f16x8 __attribute__((ext_vector_type(8)));

#define MFMA16(a, b, c)  __builtin_amdgcn_mfma_f32_16x16x32_bf16((a), (b), (c), 0, 0, 0)
#define MFMAH(a, b, c)   __builtin_amdgcn_mfma_f32_16x16x32_f16((a), (b), (c), 0, 0, 0)

// Barrier draining LDS (lgkm) but NOT in-flight global prefetch loads.
#define LGKM_BARRIER() asm volatile("s_waitcnt lgkmcnt(0)\ns_barrier" ::: "memory")

#if __has_builtin(__builtin_amdgcn_exp2f)
#define EXP2F(x) __builtin_amdgcn_exp2f(x)
#else
#define EXP2F(x) __exp2f(x)
#endif

// DPP row_shr:8 (0x118): lane l receives lane l-8 within each 16-lane row.
template <int CTRL>
__device__ inline float qdpp(float v) {
    int s = __builtin_bit_cast(int, v);
    int d = __builtin_amdgcn_update_dpp(0, s, CTRL, 0xF, 0xF, true);
    return __builtin_bit_cast(float, d);
}
#define QSHR8(v) qdpp<0x118>(v)

// Clamp-free activations (exp2 over/underflow give exact limits, no NaN).
__device__ inline float sigm_(float v) {
    return __builtin_amdgcn_rcpf(1.f + EXP2F(-1.44269504f * v));
}
__device__ inline float tanh_(float v) {
    return 1.f - 2.f * __builtin_amdgcn_rcpf(1.f + EXP2F(2.88539008f * v));
}

// ---------------- ws layout (bytes) ----------------
#define WS_BT     0               // conv weights repacked [64][640] bf16 =    81,920
#define WS_WIHB   81920           // w_ih bf16 [512][64]                  =    65,536
#define WS_POOLED 278528          // pooled bf16 [64][1024][64]           = 8,388,608
#define WS_EMB    8667136         // emb bf16 [20000][128]                = 5,120,000
#define WS_XG     8667136         // xg f16 frags: 8 bg x 1024 t x 4096   = 67,108,864
// xg per (bg,t): 8 KB block of raw C-frags; lane (w,quad,n8), gate g at
//   (g*8+w)*128 + (quad*8+n8)*4 f16   (f16x4 = the 4 C-regs, bias folded)

// ============ prep A: emb f32 -> bf16 ============
__global__ void emb_cvt_k(const float* __restrict__ emb, bf16* __restrict__ embb) {
    int g = blockIdx.x * 256 + threadIdx.x;
    f32x4 v = *(const f32x4*)(emb + g * 4);
    bf16* d = embb + g * 4;
    d[0] = (bf16)v[0]; d[1] = (bf16)v[1]; d[2] = (bf16)v[2]; d[3] = (bf16)v[3];
}

// ============ prep B: conv_w repack->bf16; w_ih->bf16 ============
__global__ void prep_small_k(const float* __restrict__ conv_w, bf16* __restrict__ bt,
                             const float* __restrict__ w_ih, bf16* __restrict__ w_ihb) {
    int g = blockIdx.x * 256 + threadIdx.x;
    if (g < 64 * 640) {
        int f = g / 640, kk = g - f * 640;
        int k = kk >> 7, e = kk & 127;
        bt[g] = (bf16)conv_w[(f * 128 + e) * 5 + k];
    } else {
        int h = g - 64 * 640;
        if (h < 512 * 64) w_ihb[h] = (bf16)w_ih[h];
    }
}

// ============ kernel 1: embed-gather + conv + ReLU + pool4 ============
__global__ __launch_bounds__(256, 2) void conv_pool_k(
    const int* __restrict__ x, const bf16* __restrict__ embb,
    const bf16* __restrict__ bt, const float* __restrict__ conv_b,
    bf16* __restrict__ pooled)
{
    __shared__ bf16 T[144 * 136];
    const int b   = blockIdx.x >> 5;
    const int l0  = (blockIdx.x & 31) << 7;
    const int tid = threadIdx.x;
    const int ln  = tid & 63, w = tid >> 6;
    const int l15 = ln & 15, quad = ln >> 4;
    const int f   = w * 16 + l15;

    bf16x8 bfrag[20];
    #pragma unroll
    for (int kc = 0; kc < 20; ++kc) {
        uint4 v = *(const uint4*)(bt + f * 640 + kc * 32 + quad * 8);
        bfrag[kc] = __builtin_bit_cast(bf16x8, v);
    }
    const float cb = conv_b[f];

    #pragma unroll
    for (int p = 0; p < 9; ++p) {
        int r = p * 16 + (tid >> 4);
        int cg = tid & 15;
        int token = l0 + r; if (token > 4095) token = 4095;
        int idx = x[b * 4096 + token];
        uint4 v = *(const uint4*)(embb + idx * 128 + cg * 8);
        *(uint4*)(&T[r * 136 + cg * 8]) = v;
    }
    __syncthreads();

    f32x4 acc[8];
    #pragma unroll
    for (int tm = 0; tm < 8; ++tm) acc[tm] = (f32x4){0.f, 0.f, 0.f, 0.f};

    #pragma unroll
    for (int kc = 0; kc < 20; ++kc) {
        const int ktap = kc >> 2;
        const int ecol = (kc & 3) * 32 + quad * 8;
        #pragma unroll
        for (int tm = 0; tm < 8; ++tm) {
            int row = tm * 16 + l15 + ktap;
            bf16x8 a = *(const bf16x8*)(&T[row * 136 + ecol]);
            acc[tm] = MFMA16(a, bfrag[kc], acc[tm]);
        }
    }

    #pragma unroll
    for (int tm = 0; tm < 8; ++tm) {
        float mx = fmaxf(fmaxf(acc[tm][0], acc[tm][1]), fmaxf(acc[tm][2], acc[tm][3]));
        mx = fmaxf(mx + cb, 0.f);
        int t = (l0 >> 2) + tm * 4 + quad;
        if (t < 1023) pooled[(b * 1024 + t) * 64 + f] = (bf16)mx;
    }
}

// ============ kernel 2: xg = raw C-frags of (w_ih @ pooled^T + bias) ============
// Grid 64 = bgp(4 groups of 16 batches) x tseg(16 x 64 t). 512 thr = 8 waves.
// Wave w computes gate-tiles (g, w): rows 128g+16w+n16, cols = 16 batches.
// Stores f16x4 C-frags (bias folded) in the LSTM's exact load layout.
__global__ __launch_bounds__(512, 2) void xg_gemm_k(
    const bf16* __restrict__ pooled, const bf16* __restrict__ w_ihb,
    const float* __restrict__ b_ih, const float* __restrict__ b_hh,
    f16* __restrict__ xg)
{
    const int bgp = blockIdx.x >> 4;
    const int tsg = blockIdx.x & 15;
    const int tid = threadIdx.x;
    const int l = tid & 63, w = tid >> 6;
    const int quad = l >> 4, n16 = l & 15;

    bf16x8 A[4][2];
    f32x4 bias4[4];
    #pragma unroll
    for (int g = 0; g < 4; ++g) {
        int row = 128 * g + 16 * w + n16;
        uint4 v0 = *(const uint4*)(w_ihb + row * 64 + quad * 8);
        uint4 v1 = *(const uint4*)(w_ihb + row * 64 + 32 + quad * 8);
        A[g][0] = __builtin_bit_cast(bf16x8, v0);
        A[g][1] = __builtin_bit_cast(bf16x8, v1);
        #pragma unroll
        for (int r = 0; r < 4; ++r) {
            int br = 128 * g + 16 * w + quad * 4 + r;
            bias4[g][r] = b_ih[br] + b_hh[br];
        }
    }

    const int batch = bgp * 16 + n16;
    const int bgo   = bgp * 2 + (n16 >> 3);
    f16* outp = xg + (size_t)bgo * 4194304 + (size_t)w * 128 + (quad * 8 + (n16 & 7)) * 4;
    const bf16* pp = pooled + (size_t)batch * 65536 + quad * 8;

    for (int i = 0; i < 64; ++i) {
        const int t = tsg * 64 + i;
        uint4 v0 = *(const uint4*)(pp + (size_t)t * 64);
        uint4 v1 = *(const uint4*)(pp + (size_t)t * 64 + 32);
        bf16x8 B0 = __builtin_bit_cast(bf16x8, v0);
        bf16x8 B1 = __builtin_bit_cast(bf16x8, v1);
        #pragma unroll
        for (int g = 0; g < 4; ++g) {
            f32x4 acc = MFMA16(A[g][0], B0, bias4[g]);
            acc = MFMA16(A[g][1], B1, acc);
            f16x4 sv = {(f16)acc[0], (f16)acc[1], (f16)acc[2], (f16)acc[3]};
            *(f16x4*)(outp + (size_t)t * 4096 + g * 1024) = sv;
        }
    }
}

// ============ kernel 3: LSTM recurrence (MFMA, 8 batches/WG) + fc head ============
// 8 WGs x 512 thr (8 waves). Wave w: A-frags = W rows {128g+16w+n16}, 4 gates
// x 4 k-chunks (64 VGPRs f16). H in LDS [row n][k] f16, stride 144, k-space
// ROTATED by 8*(n>>2) f16 per row -> per-16-lane-phase bank starts
// 4(2(n&3)+(n>>2)+q) mod 32 = 2 lanes/start = conflict-free (R9 measured
// 131k conflicts = 128 cy/step with the unrotated stride-144 layout).
// Acc init = xg C-frags (x+bias) loaded as 4x b64, distance-2 prefetch.
// H rows 8-15 stay zero -> lanes n16>=8 contribute 0*W; DPP row_shr:8 moves
// regs 2,3 of lanes n<8 to lanes n+8 so every lane updates 2 (unit,batch).
__global__ __launch_bounds__(512, 2) void lstm_fc_k(
    const f16* __restrict__ xg, const float* __restrict__ w_hh,
    const float* __restrict__ fc_w, const float* __restrict__ fc_b,
    float* __restrict__ out)
{
    __shared__ __align__(16) f16 Hb[2][16 * 144];
    const int bg  = blockIdx.x;
    const int tid = threadIdx.x;
    const int l   = tid & 63, w = tid >> 6;
    const int quad = l >> 4, n16 = l & 15;
    const int n8 = n16 & 7, rp = n16 >> 3;
    const int u0 = 16 * w + quad * 4;

    // A-frags from w_hh f32 -> f16: wf[gate][k-chunk]
    f16x8 wf[4][4];
    #pragma unroll
    for (int g = 0; g < 4; ++g) {
        const float* wr = w_hh + (128 * g + 16 * w + n16) * 128;
        #pragma unroll
        for (int c = 0; c < 4; ++c) {
            f32x4 va = *(const f32x4*)(wr + c * 32 + quad * 8);
            f32x4 vb = *(const f32x4*)(wr + c * 32 + quad * 8 + 4);
            wf[g][c] = (f16x8){(f16)va[0], (f16)va[1], (f16)va[2], (f16)va[3],
                               (f16)vb[0], (f16)vb[1], (f16)vb[2], (f16)vb[3]};
        }
    }

    // zero both H buffers (rows 8..15 stay 0 forever)
    for (int i = tid; i < 2304; i += 512) ((uint32_t*)Hb)[i] = 0;

    // per-lane xg base (lanes n16>=8 duplicate n16-8's address; values unused)
    const f16* xpl = xg + (size_t)bg * 4194304 + (size_t)w * 128 + (quad * 8 + n8) * 4;
    #define LOADX(dst, t) { _Pragma("unroll") \
        for (int g = 0; g < 4; ++g) dst[g] = *(const f16x4*)(xpl + (size_t)(t) * 4096 + g * 1024); }

    float cst0 = 0.f, cst1 = 0.f;
    int p = 0;
    const int qr = quad * 8 + 8 * (n16 >> 2);    // swizzled chunk base
    LGKM_BARRIER();

    auto step = [&](const f16x4* xc) {
        f32x4 ai = {(float)xc[0][0], (float)xc[0][1], (float)xc[0][2], (float)xc[0][3]};
        f32x4 af = {(float)xc[1][0], (float)xc[1][1], (float)xc[1][2], (float)xc[1][3]};
        f32x4 ag = {(float)xc[2][0], (float)xc[2][1], (float)xc[2][2], (float)xc[2][3]};
        f32x4 ao = {(float)xc[3][0], (float)xc[3][1], (float)xc[3][2], (float)xc[3][3]};
        const f16* hrow = &Hb[p][n16 * 144];
        f16x8 b0 = *(const f16x8*)(hrow + ( qr        & 127));
        f16x8 b1 = *(const f16x8*)(hrow + ((qr + 32)  & 127));
        f16x8 b2 = *(const f16x8*)(hrow + ((qr + 64)  & 127));
        f16x8 b3 = *(const f16x8*)(hrow + ((qr + 96)  & 127));
        ai = MFMAH(wf[0][0], b0, ai); af = MFMAH(wf[1][0], b0, af);
        ag = MFMAH(wf[2][0], b0, ag); ao = MFMAH(wf[3][0], b0, ao);
        ai = MFMAH(wf[0][1], b1, ai); af = MFMAH(wf[1][1], b1, af);
        ag = MFMAH(wf[2][1], b1, ag); ao = MFMAH(wf[3][1], b1, ao);
        ai = MFMAH(wf[0][2], b2, ai); af = MFMAH(wf[1][2], b2, af);
        ag = MFMAH(wf[2][2], b2, ag); ao = MFMAH(wf[3][2], b2, ao);
        ai = MFMAH(wf[0][3], b3, ai); af = MFMAH(wf[1][3], b3, af);
        ag = MFMAH(wf[2][3], b3, ag); ao = MFMAH(wf[3][3], b3, ao);

        float i2 = QSHR8(ai[2]), i3 = QSHR8(ai[3]);
        float f2 = QSHR8(af[2]), f3 = QSHR8(af[3]);
        float g2 = QSHR8(ag[2]), g3 = QSHR8(ag[3]);
        float o2 = QSHR8(ao[2]), o3 = QSHR8(ao[3]);
        float si0 = rp ? i2 : ai[0], si1 = rp ? i3 : ai[1];
        float sf0 = rp ? f2 : af[0], sf1 = rp ? f3 : af[1];
        float sg0 = rp ? g2 : ag[0], sg1 = rp ? g3 : ag[1];
        float so0 = rp ? o2 : ao[0], so1 = rp ? o3 : ao[1];

        float iv0 = sigm_(si0), iv1 = sigm_(si1);
        float fv0 = sigm_(sf0), fv1 = sigm_(sf1);
        float gv0 = tanh_(sg0), gv1 = tanh_(sg1);
        float ov0 = sigm_(so0), ov1 = sigm_(so1);
        cst0 = fv0 * cst0 + iv0 * gv0;
        cst1 = fv1 * cst1 + iv1 * gv1;
        f16x2 hv = {(f16)(ov0 * tanh_(cst0)), (f16)(ov1 * tanh_(cst1))};
        *(f16x2*)(&Hb[p ^ 1][n8 * 144 + ((u0 + rp * 2 + 8 * (n8 >> 2)) & 127)]) = hv;
        p ^= 1;
        LGKM_BARRIER();
    };

    f16x4 xa[4], xb[4];
    LOADX(xa, 0); LOADX(xb, 1);
    for (int s = 0; s < 1022; s += 2) {
        f16x4 xn[4]; LOADX(xn, s + 2);      // prefetch (not drained by barrier)
        step(xa);
        f16x4 xm[4]; LOADX(xm, s + 3);      // s+3 <= 1023, in-bounds
        step(xb);
        #pragma unroll
        for (int g = 0; g < 4; ++g) { xa[g] = xn[g]; xb[g] = xm[g]; }
    }
    step(xa);   // s = 1022

    // fc: out[bg*8+bb][c] = h . fc_w[c] + fc_b[c]; final h in Hb[p] (swizzled)
    if (tid < 128) {
        int bb = tid >> 4, idx = tid & 15;
        float p0 = 0.f, p1 = 0.f;
        #pragma unroll
        for (int j = 0; j < 8; ++j) {
            int k = idx * 8 + j;
            int ph = (k + 8 * (bb >> 2)) & 127;
            float hv = (float)Hb[p][bb * 144 + ph];
            p0 += hv * fc_w[k];
            p1 += hv * fc_w[128 + k];
        }
        #pragma unroll
        for (int off = 8; off > 0; off >>= 1) {
            p0 += __shfl_down(p0, off, 16);
            p1 += __shfl_down(p1, off, 16);
        }
        if (idx == 0) {
            out[(bg * 8 + bb) * 2 + 0] = p0 + fc_b[0];
            out[(bg * 8 + bb) * 2 + 1] = p1 + fc_b[1];
        }
    }
}

// ============================ launcher ============================
extern "C" void kernel_launch(void* const* d_in, const int* in_sizes, int n_in,
                              void* d_out, int out_size, void* d_ws, size_t ws_size,
                              hipStream_t stream) {
    const int*   x      = (const int*)d_in[0];
    const float* emb    = (const float*)d_in[1];
    const float* conv_w = (const float*)d_in[2];
    const float* conv_b = (const float*)d_in[3];
    const float* w_ih   = (const float*)d_in[4];
    const float* w_hh   = (const float*)d_in[5];
    const float* b_ih   = (const float*)d_in[6];
    const float* b_hh   = (const float*)d_in[7];
    const float* fc_w   = (const float*)d_in[8];
    const float* fc_b   = (const float*)d_in[9];
    float* out = (float*)d_out;

    char* ws = (char*)d_ws;
    bf16* bt     = (bf16*)(ws + WS_BT);
    bf16* w_ihb  = (bf16*)(ws + WS_WIHB);
    bf16* pooled = (bf16*)(ws + WS_POOLED);
    bf16* embb   = (bf16*)(ws + WS_EMB);
    f16*  xg     = (f16*)(ws + WS_XG);   // overlaps embb (emb dead after conv_pool)

    emb_cvt_k<<<2500, 256, 0, stream>>>(emb, embb);
    prep_small_k<<<288, 256, 0, stream>>>(conv_w, bt, w_ih, w_ihb);
    conv_pool_k<<<2048, 256, 0, stream>>>(x, embb, bt, conv_b, pooled);
    xg_gemm_k<<<64, 512, 0, stream>>>(pooled, w_ihb, b_ih, b_hh, xg);
    lstm_fc_k<<<8, 512, 0, stream>>>(xg, w_hh, fc_w, fc_b, out);
}

// Round 11
// 789.093 us; speedup vs baseline: 1.1914x; 1.1914x over previous
//
#include <hip/hip_runtime.h>
#include <stdint.h>
#include <stddef.h>

// CNNLSTM: embed -> conv1d(K=5) -> ReLU -> maxpool4 -> LSTM(T=1023,H=128) -> fc(2)
// Inputs: x int32; all float tensors float32. Output f32.
// R11: MFMA recurrence (8 WGs x 8 batches) = R9 structure with:
//  - H stride 136 f16 (conv-proven conflict-free; R10's swizzle measured 8x WORSE)
//  - x+bias pre-packed per-lane (32B) -> C-init via 2x b128 + cvt in latency
//    shadow; post-DPP tail has no adds
//  - xg_gemm at 256 WGs storing 2x b128 per (lane,t)

typedef __bf16 bf16;
typedef __bf16 bf16x8 __attribute__((ext_vector_type(8)));
typedef float  f32x4  __attribute__((ext_vector_type(4)));
typedef _Float16 f16;
typedef f16 f16x2 __attribute__((ext_vector_type(2)));
typedef f16 f16x8 __attribute__((ext_vector_type(8)));

#define MFMA16(a, b, c)  __builtin_amdgcn_mfma_f32_16x16x32_bf16((a), (b), (c), 0, 0, 0)
#define MFMAH(a, b, c)   __builtin_amdgcn_mfma_f32_16x16x32_f16((a), (b), (c), 0, 0, 0)

// Barrier draining LDS (lgkm) but NOT in-flight global prefetch loads.
#define LGKM_BARRIER() asm volatile("s_waitcnt lgkmcnt(0)\ns_barrier" ::: "memory")

#if __has_builtin(__builtin_amdgcn_exp2f)
#define EXP2F(x) __builtin_amdgcn_exp2f(x)
#else
#define EXP2F(x) __exp2f(x)
#endif

// DPP row_shr:8 (0x118): lane l receives lane l-8 within each 16-lane row;
// lanes 0-7 get 0 (bound_ctrl) -- they keep their own regs instead.
template <int CTRL>
__device__ inline float qdpp(float v) {
    int s = __builtin_bit_cast(int, v);
    int d = __builtin_amdgcn_update_dpp(0, s, CTRL, 0xF, 0xF, true);
    return __builtin_bit_cast(float, d);
}
#define QSHR8(v) qdpp<0x118>(v)

// Clamp-free activations (exp2 over/underflow give exact limits, no NaN).
__device__ inline float sigm_(float v) {
    return __builtin_amdgcn_rcpf(1.f + EXP2F(-1.44269504f * v));
}
__device__ inline float tanh_(float v) {
    return 1.f - 2.f * __builtin_amdgcn_rcpf(1.f + EXP2F(2.88539008f * v));
}

// ---------------- ws layout (bytes) ----------------
#define WS_BT     0               // conv weights repacked [64][640] bf16 =    81,920
#define WS_WIHB   81920           // w_ih bf16 [512][64]                  =    65,536
#define WS_POOLED 278528          // pooled bf16 [64][1024][64]           = 8,388,608
#define WS_EMB    8667136         // emb bf16 [20000][128]                = 5,120,000
#define WS_XG     8667136         // xg f16: 8 bg x 1024 t x 4096 vals    = 67,108,864
// xg per (bg,t): 8 KB; lane block at ((w*4+quad)*8+n8)*16 holds 16 f16:
//   [g0 r0..3][g1 r0..3][g2 r0..3][g3 r0..3]  (x + bias, MFMA C-init layout)

// ============ prep A: emb f32 -> bf16 ============
__global__ void emb_cvt_k(const float* __restrict__ emb, bf16* __restrict__ embb) {
    int g = blockIdx.x * 256 + threadIdx.x;
    f32x4 v = *(const f32x4*)(emb + g * 4);
    bf16* d = embb + g * 4;
    d[0] = (bf16)v[0]; d[1] = (bf16)v[1]; d[2] = (bf16)v[2]; d[3] = (bf16)v[3];
}

// ============ prep B: conv_w repack->bf16; w_ih->bf16 ============
__global__ void prep_small_k(const float* __restrict__ conv_w, bf16* __restrict__ bt,
                             const float* __restrict__ w_ih, bf16* __restrict__ w_ihb) {
    int g = blockIdx.x * 256 + threadIdx.x;
    if (g < 64 * 640) {
        int f = g / 640, kk = g - f * 640;
        int k = kk >> 7, e = kk & 127;
        bt[g] = (bf16)conv_w[(f * 128 + e) * 5 + k];
    } else {
        int h = g - 64 * 640;
        if (h < 512 * 64) w_ihb[h] = (bf16)w_ih[h];
    }
}

// ============ kernel 1: embed-gather + conv + ReLU + pool4 ============
__global__ __launch_bounds__(256, 2) void conv_pool_k(
    const int* __restrict__ x, const bf16* __restrict__ embb,
    const bf16* __restrict__ bt, const float* __restrict__ conv_b,
    bf16* __restrict__ pooled)
{
    __shared__ bf16 T[144 * 136];
    const int b   = blockIdx.x >> 5;
    const int l0  = (blockIdx.x & 31) << 7;
    const int tid = threadIdx.x;
    const int ln  = tid & 63, w = tid >> 6;
    const int l15 = ln & 15, quad = ln >> 4;
    const int f   = w * 16 + l15;

    bf16x8 bfrag[20];
    #pragma unroll
    for (int kc = 0; kc < 20; ++kc) {
        uint4 v = *(const uint4*)(bt + f * 640 + kc * 32 + quad * 8);
        bfrag[kc] = __builtin_bit_cast(bf16x8, v);
    }
    const float cb = conv_b[f];

    #pragma unroll
    for (int p = 0; p < 9; ++p) {
        int r = p * 16 + (tid >> 4);
        int cg = tid & 15;
        int token = l0 + r; if (token > 4095) token = 4095;
        int idx = x[b * 4096 + token];
        uint4 v = *(const uint4*)(embb + idx * 128 + cg * 8);
        *(uint4*)(&T[r * 136 + cg * 8]) = v;
    }
    __syncthreads();

    f32x4 acc[8];
    #pragma unroll
    for (int tm = 0; tm < 8; ++tm) acc[tm] = (f32x4){0.f, 0.f, 0.f, 0.f};

    #pragma unroll
    for (int kc = 0; kc < 20; ++kc) {
        const int ktap = kc >> 2;
        const int ecol = (kc & 3) * 32 + quad * 8;
        #pragma unroll
        for (int tm = 0; tm < 8; ++tm) {
            int row = tm * 16 + l15 + ktap;
            bf16x8 a = *(const bf16x8*)(&T[row * 136 + ecol]);
            acc[tm] = MFMA16(a, bfrag[kc], acc[tm]);
        }
    }

    #pragma unroll
    for (int tm = 0; tm < 8; ++tm) {
        float mx = fmaxf(fmaxf(acc[tm][0], acc[tm][1]), fmaxf(acc[tm][2], acc[tm][3]));
        mx = fmaxf(mx + cb, 0.f);
        int t = (l0 >> 2) + tm * 4 + quad;
        if (t < 1023) pooled[(b * 1024 + t) * 64 + f] = (bf16)mx;
    }
}

// ============ kernel 2: xg = C-init frags of (w_ih @ pooled^T + bias) ============
// Grid 256 = bgp(4 x 16 batches) x tsg(64 x 16 t). 512 thr = 8 waves.
// Wave w: rows 128g+16w+n16 (4 gates), cols = 16 batches. Lane stores its
// 16-f16 block (4 gates x 4 regs) as 2x b128 -- exactly the LSTM's load.
__global__ __launch_bounds__(512, 2) void xg_gemm_k(
    const bf16* __restrict__ pooled, const bf16* __restrict__ w_ihb,
    const float* __restrict__ b_ih, const float* __restrict__ b_hh,
    f16* __restrict__ xg)
{
    const int bgp = blockIdx.x >> 6;
    const int tsg = blockIdx.x & 63;
    const int tid = threadIdx.x;
    const int l = tid & 63, w = tid >> 6;
    const int quad = l >> 4, n16 = l & 15;

    bf16x8 A[4][2];
    f32x4 bias4[4];
    #pragma unroll
    for (int g = 0; g < 4; ++g) {
        int row = 128 * g + 16 * w + n16;
        uint4 v0 = *(const uint4*)(w_ihb + row * 64 + quad * 8);
        uint4 v1 = *(const uint4*)(w_ihb + row * 64 + 32 + quad * 8);
        A[g][0] = __builtin_bit_cast(bf16x8, v0);
        A[g][1] = __builtin_bit_cast(bf16x8, v1);
        #pragma unroll
        for (int r = 0; r < 4; ++r) {
            int br = 128 * g + 16 * w + quad * 4 + r;
            bias4[g][r] = b_ih[br] + b_hh[br];
        }
    }

    const int batch = bgp * 16 + n16;
    const int bgo   = bgp * 2 + (n16 >> 3);
    f16* outp = xg + (size_t)bgo * 4194304 + ((w * 4 + quad) * 8 + (n16 & 7)) * 16;
    const bf16* pp = pooled + (size_t)batch * 65536 + quad * 8;

    for (int i = 0; i < 16; ++i) {
        const int t = tsg * 16 + i;
        uint4 v0 = *(const uint4*)(pp + (size_t)t * 64);
        uint4 v1 = *(const uint4*)(pp + (size_t)t * 64 + 32);
        bf16x8 B0 = __builtin_bit_cast(bf16x8, v0);
        bf16x8 B1 = __builtin_bit_cast(bf16x8, v1);
        f32x4 a[4];
        #pragma unroll
        for (int g = 0; g < 4; ++g) {
            a[g] = MFMA16(A[g][0], B0, bias4[g]);
            a[g] = MFMA16(A[g][1], B1, a[g]);
        }
        f16x8 s0, s1;
        #pragma unroll
        for (int r = 0; r < 4; ++r) {
            s0[r] = (f16)a[0][r]; s0[4 + r] = (f16)a[1][r];
            s1[r] = (f16)a[2][r]; s1[4 + r] = (f16)a[3][r];
        }
        *(f16x8*)(outp + (size_t)t * 4096) = s0;
        *(f16x8*)(outp + (size_t)t * 4096 + 8) = s1;
    }
}

// ============ kernel 3: LSTM recurrence (MFMA, 8 batches/WG) + fc head ============
// 8 WGs x 512 thr (8 waves). Wave w: A-frags = W rows {128g+16w+n16}, 4 gates
// x 4 k-chunks (64 VGPRs f16). H in LDS [row n][k] f16, STRIDE 136 (conv-
// proven conflict-free; R9's 144 gave 16 cy/WG-step, R10's swizzle 128).
// Acc C-init = xg block (x+bias): 2x b128 + 16 cvt in the ds_read latency
// shadow -> post-DPP tail is pure activations. H rows 8-15 stay zero; C cols
// 8-15 discarded (DPP row_shr:8 redistributes regs 2,3 of lanes n<8).
__global__ __launch_bounds__(512, 2) void lstm_fc_k(
    const f16* __restrict__ xg, const float* __restrict__ w_hh,
    const float* __restrict__ fc_w, const float* __restrict__ fc_b,
    float* __restrict__ out)
{
    __shared__ __align__(16) f16 Hb[2][16 * 136];
    const int bg  = blockIdx.x;
    const int tid = threadIdx.x;
    const int l   = tid & 63, w = tid >> 6;
    const int quad = l >> 4, n16 = l & 15;
    const int n8 = n16 & 7, rp = n16 >> 3;
    const int u0 = 16 * w + quad * 4;

    // A-frags from w_hh f32 -> f16: wf[gate][k-chunk]
    f16x8 wf[4][4];
    #pragma unroll
    for (int g = 0; g < 4; ++g) {
        const float* wr = w_hh + (128 * g + 16 * w + n16) * 128;
        #pragma unroll
        for (int c = 0; c < 4; ++c) {
            f32x4 va = *(const f32x4*)(wr + c * 32 + quad * 8);
            f32x4 vb = *(const f32x4*)(wr + c * 32 + quad * 8 + 4);
            wf[g][c] = (f16x8){(f16)va[0], (f16)va[1], (f16)va[2], (f16)va[3],
                               (f16)vb[0], (f16)vb[1], (f16)vb[2], (f16)vb[3]};
        }
    }

    // zero both H buffers (rows 8..15 stay 0 forever)
    for (int i = tid; i < 2176; i += 512) ((uint32_t*)Hb)[i] = 0;

    // per-lane xg base; lanes n16>=8 alias lane n16-8 (their C is discarded)
    const f16* xpl = xg + (size_t)bg * 4194304 + ((w * 4 + quad) * 8 + n8) * 16;

    float cst0 = 0.f, cst1 = 0.f;
    int p = 0;
    LGKM_BARRIER();

    auto step = [&](f16x8 x0, f16x8 x1) {
        // C-init = x + bias (precomputed); cvts overlap the ds_read latency
        f32x4 ai = {(float)x0[0], (float)x0[1], (float)x0[2], (float)x0[3]};
        f32x4 af = {(float)x0[4], (float)x0[5], (float)x0[6], (float)x0[7]};
        f32x4 ag = {(float)x1[0], (float)x1[1], (float)x1[2], (float)x1[3]};
        f32x4 ao = {(float)x1[4], (float)x1[5], (float)x1[6], (float)x1[7]};
        const f16* hrow = &Hb[p][n16 * 136 + quad * 8];
        f16x8 b0 = *(const f16x8*)(hrow);
        f16x8 b1 = *(const f16x8*)(hrow + 32);
        f16x8 b2 = *(const f16x8*)(hrow + 64);
        f16x8 b3 = *(const f16x8*)(hrow + 96);
        ai = MFMAH(wf[0][0], b0, ai); af = MFMAH(wf[1][0], b0, af);
        ag = MFMAH(wf[2][0], b0, ag); ao = MFMAH(wf[3][0], b0, ao);
        ai = MFMAH(wf[0][1], b1, ai); af = MFMAH(wf[1][1], b1, af);
        ag = MFMAH(wf[2][1], b1, ag); ao = MFMAH(wf[3][1], b1, ao);
        ai = MFMAH(wf[0][2], b2, ai); af = MFMAH(wf[1][2], b2, af);
        ag = MFMAH(wf[2][2], b2, ag); ao = MFMAH(wf[3][2], b2, ao);
        ai = MFMAH(wf[0][3], b3, ai); af = MFMAH(wf[1][3], b3, af);
        ag = MFMAH(wf[2][3], b3, ag); ao = MFMAH(wf[3][3], b3, ao);

        // move regs 2,3 of lanes n<8 to lanes n+8 (whose own cols are dead)
        float i2 = QSHR8(ai[2]), i3 = QSHR8(ai[3]);
        float f2 = QSHR8(af[2]), f3 = QSHR8(af[3]);
        float g2 = QSHR8(ag[2]), g3 = QSHR8(ag[3]);
        float o2 = QSHR8(ao[2]), o3 = QSHR8(ao[3]);
        float si0 = rp ? i2 : ai[0], si1 = rp ? i3 : ai[1];
        float sf0 = rp ? f2 : af[0], sf1 = rp ? f3 : af[1];
        float sg0 = rp ? g2 : ag[0], sg1 = rp ? g3 : ag[1];
        float so0 = rp ? o2 : ao[0], so1 = rp ? o3 : ao[1];

        float iv0 = sigm_(si0), iv1 = sigm_(si1);
        float fv0 = sigm_(sf0), fv1 = sigm_(sf1);
        float gv0 = tanh_(sg0), gv1 = tanh_(sg1);
        float ov0 = sigm_(so0), ov1 = sigm_(so1);
        cst0 = fv0 * cst0 + iv0 * gv0;
        cst1 = fv1 * cst1 + iv1 * gv1;
        f16x2 hv = {(f16)(ov0 * tanh_(cst0)), (f16)(ov1 * tanh_(cst1))};
        *(f16x2*)(&Hb[p ^ 1][n8 * 136 + u0 + rp * 2]) = hv;
        p ^= 1;
        LGKM_BARRIER();
    };

    f16x8 xa0 = *(const f16x8*)(xpl);
    f16x8 xa1 = *(const f16x8*)(xpl + 8);
    for (int s = 0; s < 1023; ++s) {
        // prefetch t=s+1 (<=1023, in-bounds; last iteration's result unused);
        // global loads are NOT drained by the lgkm barrier -> overlap the step
        f16x8 nx0 = *(const f16x8*)(xpl + (size_t)(s + 1) * 4096);
        f16x8 nx1 = *(const f16x8*)(xpl + (size_t)(s + 1) * 4096 + 8);
        step(xa0, xa1);
        xa0 = nx0; xa1 = nx1;
    }

    // fc: out[bg*8+bb][c] = h . fc_w[c] + fc_b[c]; final h in Hb[p]
    if (tid < 128) {
        int bb = tid >> 4, idx = tid & 15;
        float p0 = 0.f, p1 = 0.f;
        #pragma unroll
        for (int j = 0; j < 8; ++j) {
            int k = idx * 8 + j;
            float hv = (float)Hb[p][bb * 136 + k];
            p0 += hv * fc_w[k];
            p1 += hv * fc_w[128 + k];
        }
        #pragma unroll
        for (int off = 8; off > 0; off >>= 1) {
            p0 += __shfl_down(p0, off, 16);
            p1 += __shfl_down(p1, off, 16);
        }
        if (idx == 0) {
            out[(bg * 8 + bb) * 2 + 0] = p0 + fc_b[0];
            out[(bg * 8 + bb) * 2 + 1] = p1 + fc_b[1];
        }
    }
}

// ============================ launcher ============================
extern "C" void kernel_launch(void* const* d_in, const int* in_sizes, int n_in,
                              void* d_out, int out_size, void* d_ws, size_t ws_size,
                              hipStream_t stream) {
    const int*   x      = (const int*)d_in[0];
    const float* emb    = (const float*)d_in[1];
    const float* conv_w = (const float*)d_in[2];
    const float* conv_b = (const float*)d_in[3];
    const float* w_ih   = (const float*)d_in[4];
    const float* w_hh   = (const float*)d_in[5];
    const float* b_ih   = (const float*)d_in[6];
    const float* b_hh   = (const float*)d_in[7];
    const float* fc_w   = (const float*)d_in[8];
    const float* fc_b   = (const float*)d_in[9];
    float* out = (float*)d_out;

    char* ws = (char*)d_ws;
    bf16* bt     = (bf16*)(ws + WS_BT);
    bf16* w_ihb  = (bf16*)(ws + WS_WIHB);
    bf16* pooled = (bf16*)(ws + WS_POOLED);
    bf16* embb   = (bf16*)(ws + WS_EMB);
    f16*  xg     = (f16*)(ws + WS_XG);   // overlaps embb (emb dead after conv_pool)

    emb_cvt_k<<<2500, 256, 0, stream>>>(emb, embb);
    prep_small_k<<<288, 256, 0, stream>>>(conv_w, bt, w_ih, w_ihb);
    conv_pool_k<<<2048, 256, 0, stream>>>(x, embb, bt, conv_b, pooled);
    xg_gemm_k<<<256, 512, 0, stream>>>(pooled, w_ihb, b_ih, b_hh, xg);
    lstm_fc_k<<<8, 512, 0, stream>>>(xg, w_hh, fc_w, fc_b, out);
}